// Round 22
// baseline (38.886 us; speedup 1.0000x reference)
//
#include <hip/hip_runtime.h>
#include <hip/hip_bf16.h>

typedef __attribute__((ext_vector_type(8))) short short8;
typedef __attribute__((ext_vector_type(4))) float f32x4;
typedef __attribute__((address_space(1))) const unsigned int glb_u32;
typedef __attribute__((address_space(3))) unsigned int lds_u32;

#define DIMD 128
#define S 128                // col-tile width (one tile = 2 stages of 64)
#define NS 64                // stripes = 8192 / S
#define NPB 32               // pos pairs live in tiles c == r + NPB
#define CPS 64               // cols per LDS stage
#define TPC 8                // col-tiles per chunk (16 stages, one A-panel)

// scale = sqrt(2 * log2(e)) so acc = 2*log2(e)*cos -> exp2(acc) = e^(cos/T);
// logit s = acc * ln2.
#define ZSCALE 1.69864363f
#define LN2 0.6931471805599453f

// ---------------- Kernel 1: normalize rows -> scaled bf16; zero accumulators -
__global__ __launch_bounds__(256) void nrm_kernel(const float* __restrict__ zi,
                                                  const float* __restrict__ zj,
                                                  __hip_bfloat16* __restrict__ zn,
                                                  float* __restrict__ out,
                                                  float* __restrict__ rowsum, int B) {
  if (blockIdx.x == 0 && threadIdx.x == 0) out[0] = 0.0f;
  int wave = threadIdx.x >> 6, lane = threadIdx.x & 63;
  int N = 2 * B;
  int row = blockIdx.x * 4 + wave;
  if (row >= N) return;
  if (lane == 0) rowsum[row] = 0.0f;
  const float* src = (row < B) ? (zi + (size_t)row * DIMD)
                               : (zj + (size_t)(row - B) * DIMD);
  float2 v = *(const float2*)(src + lane * 2);
  float ss = v.x * v.x + v.y * v.y;
  #pragma unroll
  for (int off = 32; off; off >>= 1) ss += __shfl_xor(ss, off);
  float nrm = sqrtf(ss);
  float r = ZSCALE / fmaxf(nrm, 1e-8f);
  __hip_bfloat16* dst = zn + (size_t)row * DIMD + lane * 2;
  dst[0] = __float2bfloat16(v.x * r);
  dst[1] = __float2bfloat16(v.y * r);
}

// ---------------- Kernel 2: zn*zn^T upper-triangle, sum-of-exp --------------
// R18 structure, TPC=8: block = stripe r + 8-tile chunk (<=16 stages of 64
// cols, 2x16KB LDS dbuf, ONE A-panel for all stages). One barrier per stage;
// next stage's global_load_lds issued right after the barrier (drain-free).
// ~292 blocks — the last rung of the amortization ladder (R15->R17->R18:
// 2080->1056->544 blocks = 38.0->33.3->31.8 us). Off-diag stages add
// row-sums AND mirror col-sums to rowsum[] (direct atomicAdd — R21 proved
// staging them through LDS is a net loss). Diag tile (c==r) masks j==i, no
// mirror; pos tile (c==r+NPB) also writes pos[i], pos[i+B].

#define STAGE(BUF, ST)                                                        \
  {                                                                           \
    const ushort* s_ = gsrc0 + (size_t)(ST) * (CPS * DIMD);                   \
    _Pragma("unroll")                                                         \
    for (int c_ = 0; c_ < 4; ++c_)                                            \
      __builtin_amdgcn_global_load_lds(                                       \
          (glb_u32*)(s_ + c_ * 16 * DIMD),                                    \
          (lds_u32*)&lds[BUF][(c_ * 16 + wave * 4) * DIMD], 16, 0, 0);        \
  }

#define MM4(ACC, RG, BB)                                                      \
  ACC = __builtin_amdgcn_mfma_f32_16x16x32_bf16(a[RG][0], BB[0], ACC, 0, 0, 0); \
  ACC = __builtin_amdgcn_mfma_f32_16x16x32_bf16(a[RG][1], BB[1], ACC, 0, 0, 0); \
  ACC = __builtin_amdgcn_mfma_f32_16x16x32_bf16(a[RG][2], BB[2], ACC, 0, 0, 0); \
  ACC = __builtin_amdgcn_mfma_f32_16x16x32_bf16(a[RG][3], BB[3], ACC, 0, 0, 0);

#define EPI_PLAIN(ACC, RG, SUB)                                               \
  {                                                                           \
    float e0 = __builtin_amdgcn_exp2f(ACC[0]);                                \
    float e1 = __builtin_amdgcn_exp2f(ACC[1]);                                \
    float e2 = __builtin_amdgcn_exp2f(ACC[2]);                                \
    float e3 = __builtin_amdgcn_exp2f(ACC[3]);                                \
    rs[RG][0] += e0; rs[RG][1] += e1; rs[RG][2] += e2; rs[RG][3] += e3;       \
    cs[SUB] += (e0 + e1) + (e2 + e3);                                         \
  }

#define EPI_DIAG(ACC, RG, SUB)                                                \
  {                                                                           \
    _Pragma("unroll")                                                         \
    for (int rr = 0; rr < 4; ++rr) {                                          \
      int i_ = Rr + (RG) * 16 + lh * 4 + rr;                                  \
      int jg_ = Cst + (SUB) * 16 + l15;                                       \
      if (jg_ != i_) rs[RG][rr] += __builtin_amdgcn_exp2f(ACC[rr]);           \
    }                                                                         \
  }

#define EPI_POS(ACC, RG, SUB)                                                 \
  {                                                                           \
    _Pragma("unroll")                                                         \
    for (int rr = 0; rr < 4; ++rr) {                                          \
      int i_ = Rr + (RG) * 16 + lh * 4 + rr;                                  \
      int jg_ = Cst + (SUB) * 16 + l15;                                       \
      float e = __builtin_amdgcn_exp2f(ACC[rr]);                              \
      rs[RG][rr] += e; cs[SUB] += e;                                          \
      if (jg_ == i_ + B) {                                                    \
        float s_ = ACC[rr] * LN2;                                             \
        pos[i_] = s_; pos[i_ + B] = s_;                                       \
      }                                                                       \
    }                                                                         \
  }

#define COMPUTE(EPIM, DOMIRROR)                                               \
  {                                                                           \
    float cs[4] = {0.f, 0.f, 0.f, 0.f};                                       \
    _Pragma("unroll")                                                         \
    for (int sub = 0; sub < 4; ++sub) {                                       \
      const ushort* lp = &lds[buf][(sub * 16 + l15) * DIMD];                  \
      short8 bb[4];                                                           \
      _Pragma("unroll")                                                       \
      for (int kc = 0; kc < 4; ++kc) bb[kc] = *(const short8*)(lp + roff[kc]); \
      _Pragma("unroll")                                                       \
      for (int rg = 0; rg < 2; ++rg) {                                        \
        f32x4 acc = {0.f, 0.f, 0.f, 0.f};                                     \
        MM4(acc, rg, bb)                                                      \
        EPIM(acc, rg, sub)                                                    \
      }                                                                       \
    }                                                                         \
    if (DOMIRROR) {                                                           \
      _Pragma("unroll")                                                       \
      for (int sub = 0; sub < 4; ++sub) {                                     \
        float v = cs[sub];                                                    \
        v += __shfl_xor(v, 16);                                               \
        v += __shfl_xor(v, 32);                                               \
        if (lh == 0) atomicAdd(&rowsum[Cst + sub * 16 + l15], v);             \
      }                                                                       \
    }                                                                         \
  }

__global__ __launch_bounds__(256) void sim_kernel(const __hip_bfloat16* __restrict__ znb,
                                                  float* __restrict__ rowsum,
                                                  float* __restrict__ pos, int B) {
  const ushort* zn = (const ushort*)znb;
  const int tid = threadIdx.x;
  const int wave = tid >> 6, lane = tid & 63;
  const int l15 = lane & 15, lh = lane >> 4;

  // decode (r, chunk): stripe r has ceil((NS-r)/TPC) chunks
  int rem = blockIdx.x, r = 0;
  while (rem >= ((NS - r + TPC - 1) / TPC)) { rem -= (NS - r + TPC - 1) / TPC; ++r; }
  const int cbase = r + TPC * rem;             // first col-tile of the chunk
  const int ntile = (NS - cbase < TPC) ? (NS - cbase) : TPC;
  const int nst = 2 * ntile;                   // stages (2 per tile), <= 16

  const int Rr = r * S + wave * 32;            // this wave's 32 rows

  __shared__ ushort lds[2][CPS * DIMD];        // 2 x 16 KB

  // staging source: col = cbase*128 + wave*4 + lh (+16 per call, +64 per
  // stage — both ≡ 0 mod 8 so the pre-swizzle term is invariant).
  const int myCol = wave * 4 + lh;
  const int myKb = l15 ^ (myCol & 7);
  const ushort* gsrc0 = zn + (size_t)(cbase * S + myCol) * DIMD + myKb * 8;

  STAGE(0, 0);   // stage 0 in flight while we load A

  // A fragments: 2 row-groups x 4 k-chunks — ONE panel for all 16 stages
  short8 a[2][4];
  #pragma unroll
  for (int rg = 0; rg < 2; ++rg) {
    const ushort* ar = zn + (size_t)(Rr + rg * 16 + l15) * DIMD + lh * 8;
    #pragma unroll
    for (int kc = 0; kc < 4; ++kc) a[rg][kc] = *(const short8*)(ar + kc * 32);
  }

  float rs[2][4];
  #pragma unroll
  for (int rg = 0; rg < 2; ++rg)
    #pragma unroll
    for (int rr = 0; rr < 4; ++rr) rs[rg][rr] = 0.0f;

  int roff[4];
  #pragma unroll
  for (int kc = 0; kc < 4; ++kc) roff[kc] = ((kc * 4 + lh) ^ (l15 & 7)) * 8;

  for (int st = 0; st < nst; ++st) {
    __syncthreads();                      // drain stage st (issued a phase ago)
    if (st + 1 < nst) STAGE((st + 1) & 1, st + 1);
    const int buf = st & 1;
    const int ctile = cbase + (st >> 1);
    const int Cst = (cbase * 2 + st) * CPS;   // global col base of this stage
    if (ctile == r) {
      COMPUTE(EPI_DIAG, 0)               // self tile: mask j==i, no mirror
    } else if (ctile == r + NPB) {
      COMPUTE(EPI_POS, 1)                // positive-pair tile
    } else {
      COMPUTE(EPI_PLAIN, 1)              // branch-free fast path
    }
  }

  // row-sums: reduce across the 16 lanes sharing (lane>>4), then accumulate
  #pragma unroll
  for (int rg = 0; rg < 2; ++rg) {
    #pragma unroll
    for (int rr = 0; rr < 4; ++rr) {
      #pragma unroll
      for (int off = 1; off < 16; off <<= 1)
        rs[rg][rr] += __shfl_xor(rs[rg][rr], off);
    }
  }
  if (l15 == 0) {
    #pragma unroll
    for (int rg = 0; rg < 2; ++rg)
      #pragma unroll
      for (int rr = 0; rr < 4; ++rr)
        atomicAdd(&rowsum[Rr + rg * 16 + lh * 4 + rr], rs[rg][rr]);
  }
}

// ---------------- Kernel 3: row_loss = log(sum) - pos; mean over rows -------
__global__ __launch_bounds__(256) void fin_kernel(const float* __restrict__ rowsum,
                                                  const float* __restrict__ pos,
                                                  float* __restrict__ out, int N) {
  int i = blockIdx.x * 256 + threadIdx.x;
  float li = 0.0f;
  if (i < N)
    li = __builtin_amdgcn_logf(rowsum[i]) * LN2 - pos[i];
  #pragma unroll
  for (int off = 32; off; off >>= 1) li += __shfl_xor(li, off);
  __shared__ float red[4];
  int wave = threadIdx.x >> 6, lane = threadIdx.x & 63;
  if (lane == 0) red[wave] = li;
  __syncthreads();
  if (threadIdx.x == 0) {
    float bs = red[0] + red[1] + red[2] + red[3];
    atomicAdd(out, bs / (float)N);
  }
}

extern "C" void kernel_launch(void* const* d_in, const int* in_sizes, int n_in,
                              void* d_out, int out_size, void* d_ws, size_t ws_size,
                              hipStream_t stream) {
  const float* zi = (const float*)d_in[0];
  const float* zj = (const float*)d_in[1];
  const int B = in_sizes[0] / DIMD;   // 4096
  const int N = 2 * B;                // 8192
  float* out = (float*)d_out;

  char* ws = (char*)d_ws;
  __hip_bfloat16* zn = (__hip_bfloat16*)ws;                  // 2 MB
  float* pos = (float*)(ws + (size_t)N * DIMD * 2);          // 32 KB
  float* rowsum = (float*)(ws + (size_t)N * DIMD * 2 + (size_t)N * 4);  // 32 KB

  nrm_kernel<<<N / 4, 256, 0, stream>>>(zi, zj, zn, out, rowsum, B);
  // chunks: sum over r of ceil((NS-r)/TPC)
  int nblk = 0;
  for (int r = 0; r < NS; ++r) nblk += (NS - r + TPC - 1) / TPC;
  sim_kernel<<<nblk, 256, 0, stream>>>(zn, rowsum, pos, B);
  fin_kernel<<<N / 256, 256, 0, stream>>>(rowsum, pos, out, N);
}

// Round 23
// 31.593 us; speedup vs baseline: 1.2309x; 1.2309x over previous
//
#include <hip/hip_runtime.h>
#include <hip/hip_bf16.h>

typedef __attribute__((ext_vector_type(8))) short short8;
typedef __attribute__((ext_vector_type(4))) float f32x4;
typedef __attribute__((address_space(1))) const unsigned int glb_u32;
typedef __attribute__((address_space(3))) unsigned int lds_u32;

#define DIMD 128
#define S 128                // col-tile width (one tile = 2 stages of 64)
#define NS 64                // stripes = 8192 / S
#define NPB 32               // pos pairs live in tiles c == r + NPB
#define CPS 64               // cols per LDS stage
#define TPC 4                // col-tiles per chunk (8 stages, one A-panel)
                             // R22: TPC=8 regressed (block-length imbalance
                             // tail, 38.9us); TPC=4/544 blocks is optimal.

// scale = sqrt(2 * log2(e)) so acc = 2*log2(e)*cos -> exp2(acc) = e^(cos/T);
// logit s = acc * ln2.
#define ZSCALE 1.69864363f
#define LN2 0.6931471805599453f

// ---------------- Kernel 1: normalize rows -> scaled bf16; zero accumulators -
__global__ __launch_bounds__(256) void nrm_kernel(const float* __restrict__ zi,
                                                  const float* __restrict__ zj,
                                                  __hip_bfloat16* __restrict__ zn,
                                                  float* __restrict__ out,
                                                  float* __restrict__ rowsum, int B) {
  if (blockIdx.x == 0 && threadIdx.x == 0) out[0] = 0.0f;
  int wave = threadIdx.x >> 6, lane = threadIdx.x & 63;
  int N = 2 * B;
  int row = blockIdx.x * 4 + wave;
  if (row >= N) return;
  if (lane == 0) rowsum[row] = 0.0f;
  const float* src = (row < B) ? (zi + (size_t)row * DIMD)
                               : (zj + (size_t)(row - B) * DIMD);
  float2 v = *(const float2*)(src + lane * 2);
  float ss = v.x * v.x + v.y * v.y;
  #pragma unroll
  for (int off = 32; off; off >>= 1) ss += __shfl_xor(ss, off);
  float nrm = sqrtf(ss);
  float r = ZSCALE / fmaxf(nrm, 1e-8f);
  __hip_bfloat16* dst = zn + (size_t)row * DIMD + lane * 2;
  dst[0] = __float2bfloat16(v.x * r);
  dst[1] = __float2bfloat16(v.y * r);
}

// ---------------- Kernel 2: zn*zn^T upper-triangle, sum-of-exp --------------
// SESSION-BEST (R18, 31.8us): block = stripe r + 4-tile chunk (<=8 stages of
// 64 cols, 2x16KB LDS dbuf, ONE A-panel for all stages). One barrier per
// stage; next stage's global_load_lds issued right after the barrier
// (drain-free: loads get a full compute phase to land). 544 blocks, all
// co-resident (4/CU capacity) -> zero dispatch tail. Off-diag stages add
// row-sums AND mirror col-sums to rowsum[] (direct atomicAdd — R21 proved
// staging via LDS is a net loss). Diag tile (c==r) masks j==i, no mirror;
// pos tile (c==r+NPB) also writes pos[i], pos[i+B].

#define STAGE(BUF, ST)                                                        \
  {                                                                           \
    const ushort* s_ = gsrc0 + (size_t)(ST) * (CPS * DIMD);                   \
    _Pragma("unroll")                                                         \
    for (int c_ = 0; c_ < 4; ++c_)                                            \
      __builtin_amdgcn_global_load_lds(                                       \
          (glb_u32*)(s_ + c_ * 16 * DIMD),                                    \
          (lds_u32*)&lds[BUF][(c_ * 16 + wave * 4) * DIMD], 16, 0, 0);        \
  }

#define MM4(ACC, RG, BB)                                                      \
  ACC = __builtin_amdgcn_mfma_f32_16x16x32_bf16(a[RG][0], BB[0], ACC, 0, 0, 0); \
  ACC = __builtin_amdgcn_mfma_f32_16x16x32_bf16(a[RG][1], BB[1], ACC, 0, 0, 0); \
  ACC = __builtin_amdgcn_mfma_f32_16x16x32_bf16(a[RG][2], BB[2], ACC, 0, 0, 0); \
  ACC = __builtin_amdgcn_mfma_f32_16x16x32_bf16(a[RG][3], BB[3], ACC, 0, 0, 0);

#define EPI_PLAIN(ACC, RG, SUB)                                               \
  {                                                                           \
    float e0 = __builtin_amdgcn_exp2f(ACC[0]);                                \
    float e1 = __builtin_amdgcn_exp2f(ACC[1]);                                \
    float e2 = __builtin_amdgcn_exp2f(ACC[2]);                                \
    float e3 = __builtin_amdgcn_exp2f(ACC[3]);                                \
    rs[RG][0] += e0; rs[RG][1] += e1; rs[RG][2] += e2; rs[RG][3] += e3;       \
    cs[SUB] += (e0 + e1) + (e2 + e3);                                         \
  }

#define EPI_DIAG(ACC, RG, SUB)                                                \
  {                                                                           \
    _Pragma("unroll")                                                         \
    for (int rr = 0; rr < 4; ++rr) {                                          \
      int i_ = Rr + (RG) * 16 + lh * 4 + rr;                                  \
      int jg_ = Cst + (SUB) * 16 + l15;                                       \
      if (jg_ != i_) rs[RG][rr] += __builtin_amdgcn_exp2f(ACC[rr]);           \
    }                                                                         \
  }

#define EPI_POS(ACC, RG, SUB)                                                 \
  {                                                                           \
    _Pragma("unroll")                                                         \
    for (int rr = 0; rr < 4; ++rr) {                                          \
      int i_ = Rr + (RG) * 16 + lh * 4 + rr;                                  \
      int jg_ = Cst + (SUB) * 16 + l15;                                       \
      float e = __builtin_amdgcn_exp2f(ACC[rr]);                              \
      rs[RG][rr] += e; cs[SUB] += e;                                          \
      if (jg_ == i_ + B) {                                                    \
        float s_ = ACC[rr] * LN2;                                             \
        pos[i_] = s_; pos[i_ + B] = s_;                                       \
      }                                                                       \
    }                                                                         \
  }

#define COMPUTE(EPIM, DOMIRROR)                                               \
  {                                                                           \
    float cs[4] = {0.f, 0.f, 0.f, 0.f};                                       \
    _Pragma("unroll")                                                         \
    for (int sub = 0; sub < 4; ++sub) {                                       \
      const ushort* lp = &lds[buf][(sub * 16 + l15) * DIMD];                  \
      short8 bb[4];                                                           \
      _Pragma("unroll")                                                       \
      for (int kc = 0; kc < 4; ++kc) bb[kc] = *(const short8*)(lp + roff[kc]); \
      _Pragma("unroll")                                                       \
      for (int rg = 0; rg < 2; ++rg) {                                        \
        f32x4 acc = {0.f, 0.f, 0.f, 0.f};                                     \
        MM4(acc, rg, bb)                                                      \
        EPIM(acc, rg, sub)                                                    \
      }                                                                       \
    }                                                                         \
    if (DOMIRROR) {                                                           \
      _Pragma("unroll")                                                       \
      for (int sub = 0; sub < 4; ++sub) {                                     \
        float v = cs[sub];                                                    \
        v += __shfl_xor(v, 16);                                               \
        v += __shfl_xor(v, 32);                                               \
        if (lh == 0) atomicAdd(&rowsum[Cst + sub * 16 + l15], v);             \
      }                                                                       \
    }                                                                         \
  }

__global__ __launch_bounds__(256) void sim_kernel(const __hip_bfloat16* __restrict__ znb,
                                                  float* __restrict__ rowsum,
                                                  float* __restrict__ pos, int B) {
  const ushort* zn = (const ushort*)znb;
  const int tid = threadIdx.x;
  const int wave = tid >> 6, lane = tid & 63;
  const int l15 = lane & 15, lh = lane >> 4;

  // decode (r, chunk): stripe r has ceil((NS-r)/TPC) chunks
  int rem = blockIdx.x, r = 0;
  while (rem >= ((NS - r + TPC - 1) / TPC)) { rem -= (NS - r + TPC - 1) / TPC; ++r; }
  const int cbase = r + TPC * rem;             // first col-tile of the chunk
  const int ntile = (NS - cbase < TPC) ? (NS - cbase) : TPC;
  const int nst = 2 * ntile;                   // stages (2 per tile), <= 8

  const int Rr = r * S + wave * 32;            // this wave's 32 rows

  __shared__ ushort lds[2][CPS * DIMD];        // 2 x 16 KB

  // staging source: col = cbase*128 + wave*4 + lh (+16 per call, +64 per
  // stage — both ≡ 0 mod 8 so the pre-swizzle term is invariant).
  const int myCol = wave * 4 + lh;
  const int myKb = l15 ^ (myCol & 7);
  const ushort* gsrc0 = zn + (size_t)(cbase * S + myCol) * DIMD + myKb * 8;

  STAGE(0, 0);   // stage 0 in flight while we load A

  // A fragments: 2 row-groups x 4 k-chunks — ONE panel for all 8 stages
  short8 a[2][4];
  #pragma unroll
  for (int rg = 0; rg < 2; ++rg) {
    const ushort* ar = zn + (size_t)(Rr + rg * 16 + l15) * DIMD + lh * 8;
    #pragma unroll
    for (int kc = 0; kc < 4; ++kc) a[rg][kc] = *(const short8*)(ar + kc * 32);
  }

  float rs[2][4];
  #pragma unroll
  for (int rg = 0; rg < 2; ++rg)
    #pragma unroll
    for (int rr = 0; rr < 4; ++rr) rs[rg][rr] = 0.0f;

  int roff[4];
  #pragma unroll
  for (int kc = 0; kc < 4; ++kc) roff[kc] = ((kc * 4 + lh) ^ (l15 & 7)) * 8;

  for (int st = 0; st < nst; ++st) {
    __syncthreads();                      // drain stage st (issued a phase ago)
    if (st + 1 < nst) STAGE((st + 1) & 1, st + 1);
    const int buf = st & 1;
    const int ctile = cbase + (st >> 1);
    const int Cst = (cbase * 2 + st) * CPS;   // global col base of this stage
    if (ctile == r) {
      COMPUTE(EPI_DIAG, 0)               // self tile: mask j==i, no mirror
    } else if (ctile == r + NPB) {
      COMPUTE(EPI_POS, 1)                // positive-pair tile
    } else {
      COMPUTE(EPI_PLAIN, 1)              // branch-free fast path
    }
  }

  // row-sums: reduce across the 16 lanes sharing (lane>>4), then accumulate
  #pragma unroll
  for (int rg = 0; rg < 2; ++rg) {
    #pragma unroll
    for (int rr = 0; rr < 4; ++rr) {
      #pragma unroll
      for (int off = 1; off < 16; off <<= 1)
        rs[rg][rr] += __shfl_xor(rs[rg][rr], off);
    }
  }
  if (l15 == 0) {
    #pragma unroll
    for (int rg = 0; rg < 2; ++rg)
      #pragma unroll
      for (int rr = 0; rr < 4; ++rr)
        atomicAdd(&rowsum[Rr + rg * 16 + lh * 4 + rr], rs[rg][rr]);
  }
}

// ---------------- Kernel 3: row_loss = log(sum) - pos; mean over rows -------
__global__ __launch_bounds__(256) void fin_kernel(const float* __restrict__ rowsum,
                                                  const float* __restrict__ pos,
                                                  float* __restrict__ out, int N) {
  int i = blockIdx.x * 256 + threadIdx.x;
  float li = 0.0f;
  if (i < N)
    li = __builtin_amdgcn_logf(rowsum[i]) * LN2 - pos[i];
  #pragma unroll
  for (int off = 32; off; off >>= 1) li += __shfl_xor(li, off);
  __shared__ float red[4];
  int wave = threadIdx.x >> 6, lane = threadIdx.x & 63;
  if (lane == 0) red[wave] = li;
  __syncthreads();
  if (threadIdx.x == 0) {
    float bs = red[0] + red[1] + red[2] + red[3];
    atomicAdd(out, bs / (float)N);
  }
}

extern "C" void kernel_launch(void* const* d_in, const int* in_sizes, int n_in,
                              void* d_out, int out_size, void* d_ws, size_t ws_size,
                              hipStream_t stream) {
  const float* zi = (const float*)d_in[0];
  const float* zj = (const float*)d_in[1];
  const int B = in_sizes[0] / DIMD;   // 4096
  const int N = 2 * B;                // 8192
  float* out = (float*)d_out;

  char* ws = (char*)d_ws;
  __hip_bfloat16* zn = (__hip_bfloat16*)ws;                  // 2 MB
  float* pos = (float*)(ws + (size_t)N * DIMD * 2);          // 32 KB
  float* rowsum = (float*)(ws + (size_t)N * DIMD * 2 + (size_t)N * 4);  // 32 KB

  nrm_kernel<<<N / 4, 256, 0, stream>>>(zi, zj, zn, out, rowsum, B);
  // chunks: sum over r of ceil((NS-r)/4) = 544
  int nblk = 0;
  for (int r = 0; r < NS; ++r) nblk += (NS - r + TPC - 1) / TPC;
  sim_kernel<<<nblk, 256, 0, stream>>>(zn, rowsum, pos, B);
  fin_kernel<<<N / 256, 256, 0, stream>>>(rowsum, pos, out, N);
}